// Round 9
// baseline (955.442 us; speedup 1.0000x reference)
//
#include <hip/hip_runtime.h>
#include <hip/hip_bf16.h>

// MiniMax MoE top-2, MI355X. T=2048, H=2048, F=4096, E=8.
// Round 9: LDS-issue-balance restructure.
// gemm1: BM256xBN128, 8 waves 4mx2n, wave 64x64 per (g,u), acc 128 AGPR.
// gemm2: BM128xBN256, 8 n-waves, wave 128x32, acc 64 AGPR, ~264 blocks (~1/CU).
// Round-5-proven staging maps (0 conflicts), reg-prefetch, setprio.

#define T_TOK 2048
#define H_DIM 2048
#define F_DIM 4096
#define E_NUM 8
#define NPAIR (T_TOK * 2)

typedef __attribute__((ext_vector_type(8))) short short8;
typedef __attribute__((ext_vector_type(4))) float f32x4;

__device__ __forceinline__ unsigned short f2bf(float f) {
    unsigned u = __builtin_bit_cast(unsigned, f);
    u = (u + 0x7FFFu + ((u >> 16) & 1u)) >> 16;   // RNE
    return (unsigned short)u;
}

__device__ __forceinline__ uint4 pack8(float4 a, float4 b) {
    uint4 o;
    o.x = f2bf(a.x) | ((unsigned)f2bf(a.y) << 16);
    o.y = f2bf(a.z) | ((unsigned)f2bf(a.w) << 16);
    o.z = f2bf(b.x) | ((unsigned)f2bf(b.y) << 16);
    o.w = f2bf(b.z) | ((unsigned)f2bf(b.w) << 16);
    return o;
}

__device__ __forceinline__ uint2 pack4(float4 a) {
    uint2 o;
    o.x = f2bf(a.x) | ((unsigned)f2bf(a.y) << 16);
    o.y = f2bf(a.z) | ((unsigned)f2bf(a.w) << 16);
    return o;
}

// ---- x fp32 -> bf16 ----------------------------------------------------
__global__ void k_cvt_x(const float* __restrict__ x, ushort* __restrict__ xb) {
    int i = blockIdx.x * blockDim.x + threadIdx.x;
    const float4* p = (const float4*)x + (size_t)i * 2;
    uint2 lo = pack4(p[0]), hi = pack4(p[1]);
    ((uint4*)xb)[i] = make_uint4(lo.x, lo.y, hi.x, hi.y);
}

// ---- router ------------------------------------------------------------
__global__ void k_router(const float* __restrict__ x, const float* __restrict__ gw,
                         int2* __restrict__ eidx, float2* __restrict__ ew,
                         int* __restrict__ cnt) {
    int t = blockIdx.x * 4 + (threadIdx.x >> 6);
    int lane = threadIdx.x & 63;
    const float* xr = x + (size_t)t * H_DIM;
    float l[E_NUM];
    #pragma unroll
    for (int e = 0; e < E_NUM; e++) {
        const float* wr = gw + (size_t)e * H_DIM;
        float acc = 0.f;
        for (int i = lane; i < H_DIM; i += 64) acc += xr[i] * wr[i];
        #pragma unroll
        for (int o = 32; o; o >>= 1) acc += __shfl_xor(acc, o);
        l[e] = acc;
    }
    if (lane == 0) {
        int e0 = 0;
        #pragma unroll
        for (int e = 1; e < E_NUM; e++) if (l[e] > l[e0]) e0 = e;
        int e1 = -1;
        #pragma unroll
        for (int e = 0; e < E_NUM; e++) {
            if (e == e0) continue;
            if (e1 < 0 || l[e] > l[e1]) e1 = e;
        }
        float s1 = expf(l[e1] - l[e0]);
        float w0 = 1.f / (1.f + s1);
        float w1 = s1 * w0;
        eidx[t] = make_int2(e0, e1);
        ew[t]   = make_float2(w0, w1);
        atomicAdd(&cnt[e0], 1);
        atomicAdd(&cnt[e1], 1);
    }
}

__global__ void k_off(const int* __restrict__ cnt, int* __restrict__ off,
                      int* __restrict__ cnt2) {
    if (threadIdx.x == 0) {
        int s = 0;
        for (int e = 0; e < E_NUM; e++) { off[e] = s; s += cnt[e]; cnt2[e] = 0; }
        off[E_NUM] = s;
    }
}

__global__ void k_fill(const int2* __restrict__ eidx, const float2* __restrict__ ew,
                       const int* __restrict__ off, int* __restrict__ cnt2,
                       int* __restrict__ ptok, int2* __restrict__ inv) {
    int t = blockIdx.x * blockDim.x + threadIdx.x;
    if (t >= T_TOK) return;
    int2 e = eidx[t];
    int p0 = off[e.x] + atomicAdd(&cnt2[e.x], 1);
    ptok[p0] = t;
    int p1 = off[e.y] + atomicAdd(&cnt2[e.y], 1);
    ptok[p1] = t;
    inv[t] = make_int2(p0, p1);
}

// ---- grouped GEMM1: h = silu(X Wg^T) * (X Wu^T) ------------------------
// BM=256 x BN=128 x BK=64, 512 thr = 8 waves (4m x 2n), wave 64x64 per type.
__global__ __launch_bounds__(512, 1) void k_gemm1(
        const ushort* __restrict__ xb, const float* __restrict__ wg,
        const float* __restrict__ wu, const int* __restrict__ ptok,
        const int* __restrict__ off, ushort* __restrict__ hbuf) {
    __shared__ __align__(16) ushort As[256 * 64];   // 32 KB
    __shared__ __align__(16) ushort Bg[128 * 64];   // 16 KB
    __shared__ __align__(16) ushort Bu[128 * 64];   // 16 KB

    int e = blockIdx.y >> 4, mt = blockIdx.y & 15;
    int base = off[e], ne = off[e + 1] - base;
    int row0 = mt * 256;
    if (row0 >= ne) return;
    int nb = blockIdx.x * 128;

    int tid = threadIdx.x;
    int wv = tid >> 6, l = tid & 63;
    int lr = l & 15, lk = l >> 4;
    int wm = wv >> 1, wn = wv & 1;

    // A staging: 2 thr/row (256 rows), 4x16B slots (round-5-proven map)
    int arow = tid >> 1, ah = (tid & 1) * 4;
    int p = base + min(row0 + arow, ne - 1);
    const ushort* xrow = xb + (size_t)ptok[p] * H_DIM;
    int asw = (arow & 7) << 4;
    int ao[4];
    #pragma unroll
    for (int j = 0; j < 4; j++)
        ao[j] = arow * 64 + ((((ah + j) * 16) ^ asw) >> 1);

    // B staging: 4 thr/row (128 rows), 16 floats -> 2x16B slots (round-5 map)
    int brow = tid >> 2, bs = tid & 3;
    const float* wgrow = wg + ((size_t)e * F_DIM + nb + brow) * H_DIM + bs * 16;
    const float* wurow = wu + ((size_t)e * F_DIM + nb + brow) * H_DIM + bs * 16;
    int bsw = (brow & 7) << 4;
    int bo0 = brow * 64 + (((bs * 32) ^ bsw) >> 1);
    int bo1 = brow * 64 + (((bs * 32 + 16) ^ bsw) >> 1);

    int rsw = (lr & 7) << 4;

    f32x4 accg[4][4] = {}; f32x4 accu[4][4] = {};

    // prologue: prefetch tile 0 (A 16 regs, B 32 regs)
    uint4 pa[4]; float4 pg[4], pu[4];
    #pragma unroll
    for (int j = 0; j < 4; j++) pa[j] = *(const uint4*)(xrow + (ah + j) * 8);
    #pragma unroll
    for (int j = 0; j < 4; j++) pg[j] = *(const float4*)(wgrow + j * 4);
    #pragma unroll
    for (int j = 0; j < 4; j++) pu[j] = *(const float4*)(wurow + j * 4);

    const int NT = H_DIM / 64;
    for (int kt = 0; kt < NT; kt++) {
        __syncthreads();   // (a): vm-wait == ds_write dependency
        #pragma unroll
        for (int j = 0; j < 4; j++) *(uint4*)(&As[ao[j]]) = pa[j];
        *(uint4*)(&Bg[bo0]) = pack8(pg[0], pg[1]);
        *(uint4*)(&Bg[bo1]) = pack8(pg[2], pg[3]);
        *(uint4*)(&Bu[bo0]) = pack8(pu[0], pu[1]);
        *(uint4*)(&Bu[bo1]) = pack8(pu[2], pu[3]);
        __syncthreads();   // (b)
        if (kt + 1 < NT) {
            int kb = (kt + 1) * 64;
            #pragma unroll
            for (int j = 0; j < 4; j++)
                pa[j] = *(const uint4*)(xrow + kb + (ah + j) * 8);
            #pragma unroll
            for (int j = 0; j < 4; j++) pg[j] = *(const float4*)(wgrow + kb + j * 4);
            #pragma unroll
            for (int j = 0; j < 4; j++) pu[j] = *(const float4*)(wurow + kb + j * 4);
        }
        __builtin_amdgcn_s_setprio(1);
        #pragma unroll
        for (int kk = 0; kk < 2; kk++) {
            int kby = kk * 64 + lk * 16;
            short8 a[4];
            #pragma unroll
            for (int m = 0; m < 4; m++) {
                int row = wm * 64 + m * 16 + lr;
                a[m] = *(const short8*)(&As[(row * 128 + (kby ^ rsw)) >> 1]);
            }
            #pragma unroll
            for (int n = 0; n < 4; n++) {
                int rowb = wn * 64 + n * 16 + lr;
                int boff = (rowb * 128 + (kby ^ rsw)) >> 1;
                short8 bg8 = *(const short8*)(&Bg[boff]);
                short8 bu8 = *(const short8*)(&Bu[boff]);
                #pragma unroll
                for (int m = 0; m < 4; m++) {
                    accg[m][n] = __builtin_amdgcn_mfma_f32_16x16x32_bf16(a[m], bg8, accg[m][n], 0, 0, 0);
                    accu[m][n] = __builtin_amdgcn_mfma_f32_16x16x32_bf16(a[m], bu8, accu[m][n], 0, 0, 0);
                }
            }
        }
        __builtin_amdgcn_s_setprio(0);
    }

    // epilogue: silu(g)*u (C map: col=lane&15, row=(lane>>4)*4+r)
    #pragma unroll
    for (int m = 0; m < 4; m++) {
        #pragma unroll
        for (int r = 0; r < 4; r++) {
            int lrow = wm * 64 + m * 16 + lk * 4 + r;
            if (row0 + lrow < ne) {
                size_t rb = (size_t)(base + row0 + lrow) * F_DIM + nb;
                #pragma unroll
                for (int n = 0; n < 4; n++) {
                    float g = accg[m][n][r], u = accu[m][n][r];
                    float hv = g / (1.f + __expf(-g)) * u;
                    hbuf[rb + wn * 64 + n * 16 + lr] = f2bf(hv);
                }
            }
        }
    }
}

// ---- grouped GEMM2: ybuf[p] = h[p] Wd^T --------------------------------
// BM=128 x BN=256 x BK=64, 512 thr = 8 n-waves, wave tile 128x32 (m=8,n=2).
__global__ __launch_bounds__(512, 1) void k_gemm2(
        const ushort* __restrict__ hbuf, const float* __restrict__ wd,
        const int* __restrict__ off, float* __restrict__ ybuf) {
    __shared__ __align__(16) ushort As[128 * 64];   // 16 KB
    __shared__ __align__(16) ushort Bs[256 * 64];   // 32 KB

    int e = blockIdx.y >> 5, mt = blockIdx.y & 31;
    int base = off[e], ne = off[e + 1] - base;
    int row0 = mt * 128;
    if (row0 >= ne) return;
    int nb = blockIdx.x * 256;

    int tid = threadIdx.x;
    int wv = tid >> 6, l = tid & 63;   // wv = n-wave (cols wv*32)
    int lr = l & 15, lk = l >> 4;

    // A staging: 4 thr/row (128 rows), 2 ADJACENT 16B slots (round-5 B-map)
    int arow = tid >> 2, as2 = tid & 3;
    int p = base + min(row0 + arow, ne - 1);
    const ushort* hrow = hbuf + (size_t)p * F_DIM;
    int asw = (arow & 7) << 4;
    int ao0 = arow * 64 + (((as2 * 32) ^ asw) >> 1);
    int ao1 = arow * 64 + (((as2 * 32 + 16) ^ asw) >> 1);

    // B staging: 2 thr/row (256 rows), 4x16B slots (round-5 A-map)
    int brow = tid >> 1, bh = (tid & 1) * 4;
    const float* wdrow = wd + ((size_t)e * H_DIM + nb + brow) * F_DIM + bh * 8;
    int bsw = (brow & 7) << 4;
    int bo[4];
    #pragma unroll
    for (int j = 0; j < 4; j++)
        bo[j] = brow * 64 + ((((bh + j) * 16) ^ bsw) >> 1);

    int rsw = (lr & 7) << 4;

    f32x4 acc[8][2] = {};

    // prologue: prefetch (A 8 regs, B 32 regs)
    uint4 pa0, pa1; float4 pb[8];
    pa0 = *(const uint4*)(hrow + as2 * 16);
    pa1 = *(const uint4*)(hrow + as2 * 16 + 8);
    #pragma unroll
    for (int j = 0; j < 4; j++) {
        pb[2 * j]     = *(const float4*)(wdrow + j * 8);
        pb[2 * j + 1] = *(const float4*)(wdrow + j * 8 + 4);
    }

    const int NT = F_DIM / 64;
    for (int kt = 0; kt < NT; kt++) {
        __syncthreads();   // (a)
        *(uint4*)(&As[ao0]) = pa0;
        *(uint4*)(&As[ao1]) = pa1;
        #pragma unroll
        for (int j = 0; j < 4; j++)
            *(uint4*)(&Bs[bo[j]]) = pack8(pb[2 * j], pb[2 * j + 1]);
        __syncthreads();   // (b)
        if (kt + 1 < NT) {
            int kb = (kt + 1) * 64;
            pa0 = *(const uint4*)(hrow + kb + as2 * 16);
            pa1 = *(const uint4*)(hrow + kb + as2 * 16 + 8);
            #pragma unroll
            for (int j = 0; j < 4; j++) {
                pb[2 * j]     = *(const float4*)(wdrow + kb + j * 8);
                pb[2 * j + 1] = *(const float4*)(wdrow + kb + j * 8 + 4);
            }
        }
        __builtin_amdgcn_s_setprio(1);
        #pragma unroll
        for (int kk = 0; kk < 2; kk++) {
            int kby = kk * 64 + lk * 16;
            short8 a[8];
            #pragma unroll
            for (int m = 0; m < 8; m++) {
                int row = m * 16 + lr;
                a[m] = *(const short8*)(&As[(row * 128 + (kby ^ rsw)) >> 1]);
            }
            #pragma unroll
            for (int n = 0; n < 2; n++) {
                int rowb = wv * 32 + n * 16 + lr;
                short8 b8 = *(const short8*)(&Bs[(rowb * 128 + (kby ^ rsw)) >> 1]);
                #pragma unroll
                for (int m = 0; m < 8; m++)
                    acc[m][n] = __builtin_amdgcn_mfma_f32_16x16x32_bf16(a[m], b8, acc[m][n], 0, 0, 0);
            }
        }
        __builtin_amdgcn_s_setprio(0);
    }

    #pragma unroll
    for (int m = 0; m < 8; m++) {
        #pragma unroll
        for (int r = 0; r < 4; r++) {
            int lrow = m * 16 + lk * 4 + r;
            if (row0 + lrow < ne) {
                float* yrow = ybuf + (size_t)(base + row0 + lrow) * H_DIM + nb;
                #pragma unroll
                for (int n = 0; n < 2; n++)
                    yrow[wv * 32 + n * 16 + lr] = acc[m][n][r];
            }
        }
    }
}

// ---- combine: out[t] = w0*y[p0] + w1*y[p1] -----------------------------
__global__ void k_combine(const float* __restrict__ ybuf,
                          const float2* __restrict__ ew,
                          const int2* __restrict__ inv,
                          float* __restrict__ out) {
    int t = blockIdx.x;
    float2 w = ew[t];
    int2 pp = inv[t];
    const float4* y0 = (const float4*)(ybuf + (size_t)pp.x * H_DIM);
    const float4* y1 = (const float4*)(ybuf + (size_t)pp.y * H_DIM);
    float4* o = (float4*)(out + (size_t)t * H_DIM);
    for (int j = threadIdx.x; j < H_DIM / 4; j += blockDim.x) {
        float4 a = y0[j], b = y1[j];
        float4 r;
        r.x = w.x * a.x + w.y * b.x;
        r.y = w.x * a.y + w.y * b.y;
        r.z = w.x * a.z + w.y * b.z;
        r.w = w.x * a.w + w.y * b.w;
        o[j] = r;
    }
}

extern "C" void kernel_launch(void* const* d_in, const int* in_sizes, int n_in,
                              void* d_out, int out_size, void* d_ws, size_t ws_size,
                              hipStream_t stream) {
    const float* x  = (const float*)d_in[0];
    const float* gw = (const float*)d_in[1];
    const float* wg = (const float*)d_in[2];
    const float* wu = (const float*)d_in[3];
    const float* wd = (const float*)d_in[4];
    float* out = (float*)d_out;

    char* ws = (char*)d_ws;
    size_t o = 0;
    ushort* xb   = (ushort*)(ws + o); o += (size_t)T_TOK * H_DIM * 2;   //  8 MB
    ushort* hbuf = (ushort*)(ws + o); o += (size_t)NPAIR * F_DIM * 2;   // 32 MB
    float*  ybuf = (float*) (ws + o); o += (size_t)NPAIR * H_DIM * 4;   // 32 MB
    int*    ptok = (int*)   (ws + o); o += NPAIR * 4;
    int2*   eidx = (int2*)  (ws + o); o += T_TOK * 8;
    float2* ew   = (float2*)(ws + o); o += T_TOK * 8;
    int2*   inv  = (int2*)  (ws + o); o += T_TOK * 8;
    int*    cnt  = (int*)   (ws + o); o += 256;
    int*    cnt2 = (int*)   (ws + o); o += 256;
    int*    off  = (int*)   (ws + o); o += 256;

    hipMemsetAsync(cnt, 0, 256, stream);

    k_cvt_x <<<T_TOK * H_DIM / 8 / 256, 256, 0, stream>>>(x, xb);
    k_router<<<T_TOK / 4, 256, 0, stream>>>(x, gw, eidx, ew, cnt);
    k_off   <<<1, 64, 0, stream>>>(cnt, off, cnt2);
    k_fill  <<<T_TOK / 256, 256, 0, stream>>>(eidx, ew, off, cnt2, ptok, inv);

    dim3 g1(F_DIM / 128, E_NUM * 16);    // x: ntile(128), y: e*16 + mtile(256)
    k_gemm1<<<g1, 512, 0, stream>>>(xb, wg, wu, ptok, off, hbuf);
    dim3 g2(H_DIM / 256, E_NUM * 32);    // x: ntile(256), y: e*32 + mtile(128)
    k_gemm2<<<g2, 512, 0, stream>>>(hbuf, wd, off, ybuf);
    k_combine<<<T_TOK, 256, 0, stream>>>(ybuf, ew, inv, out);
}

// Round 10
// 710.140 us; speedup vs baseline: 1.3454x; 1.3454x over previous
//
#include <hip/hip_runtime.h>
#include <hip/hip_bf16.h>

// MiniMax MoE top-2, MI355X. T=2048, H=2048, F=4096, E=8.
// Round 10: exact round-5 GEMM bodies (best proven: 592us) + XCD-chunk
// swizzled 1D grids: siblings sharing weight panels (mt innermost) and
// A panels (nb next) land contiguously on one XCD -> re-reads served by L2.

#define T_TOK 2048
#define H_DIM 2048
#define F_DIM 4096
#define E_NUM 8
#define NPAIR (T_TOK * 2)

typedef __attribute__((ext_vector_type(8))) short short8;
typedef __attribute__((ext_vector_type(4))) float f32x4;

__device__ __forceinline__ unsigned short f2bf(float f) {
    unsigned u = __builtin_bit_cast(unsigned, f);
    u = (u + 0x7FFFu + ((u >> 16) & 1u)) >> 16;   // RNE
    return (unsigned short)u;
}

__device__ __forceinline__ uint4 pack8(float4 a, float4 b) {
    uint4 o;
    o.x = f2bf(a.x) | ((unsigned)f2bf(a.y) << 16);
    o.y = f2bf(a.z) | ((unsigned)f2bf(a.w) << 16);
    o.z = f2bf(b.x) | ((unsigned)f2bf(b.y) << 16);
    o.w = f2bf(b.z) | ((unsigned)f2bf(b.w) << 16);
    return o;
}

__device__ __forceinline__ uint2 pack4(float4 a) {
    uint2 o;
    o.x = f2bf(a.x) | ((unsigned)f2bf(a.y) << 16);
    o.y = f2bf(a.z) | ((unsigned)f2bf(a.w) << 16);
    return o;
}

// ---- x fp32 -> bf16 ----------------------------------------------------
__global__ void k_cvt_x(const float* __restrict__ x, ushort* __restrict__ xb) {
    int i = blockIdx.x * blockDim.x + threadIdx.x;
    const float4* p = (const float4*)x + (size_t)i * 2;
    uint2 lo = pack4(p[0]), hi = pack4(p[1]);
    ((uint4*)xb)[i] = make_uint4(lo.x, lo.y, hi.x, hi.y);
}

// ---- router ------------------------------------------------------------
__global__ void k_router(const float* __restrict__ x, const float* __restrict__ gw,
                         int2* __restrict__ eidx, float2* __restrict__ ew,
                         int* __restrict__ cnt) {
    int t = blockIdx.x * 4 + (threadIdx.x >> 6);
    int lane = threadIdx.x & 63;
    const float* xr = x + (size_t)t * H_DIM;
    float l[E_NUM];
    #pragma unroll
    for (int e = 0; e < E_NUM; e++) {
        const float* wr = gw + (size_t)e * H_DIM;
        float acc = 0.f;
        for (int i = lane; i < H_DIM; i += 64) acc += xr[i] * wr[i];
        #pragma unroll
        for (int o = 32; o; o >>= 1) acc += __shfl_xor(acc, o);
        l[e] = acc;
    }
    if (lane == 0) {
        int e0 = 0;
        #pragma unroll
        for (int e = 1; e < E_NUM; e++) if (l[e] > l[e0]) e0 = e;
        int e1 = -1;
        #pragma unroll
        for (int e = 0; e < E_NUM; e++) {
            if (e == e0) continue;
            if (e1 < 0 || l[e] > l[e1]) e1 = e;
        }
        float s1 = expf(l[e1] - l[e0]);
        float w0 = 1.f / (1.f + s1);
        float w1 = s1 * w0;
        eidx[t] = make_int2(e0, e1);
        ew[t]   = make_float2(w0, w1);
        atomicAdd(&cnt[e0], 1);
        atomicAdd(&cnt[e1], 1);
    }
}

__global__ void k_off(const int* __restrict__ cnt, int* __restrict__ off,
                      int* __restrict__ cnt2) {
    if (threadIdx.x == 0) {
        int s = 0;
        for (int e = 0; e < E_NUM; e++) { off[e] = s; s += cnt[e]; cnt2[e] = 0; }
        off[E_NUM] = s;
    }
}

__global__ void k_fill(const int2* __restrict__ eidx, const float2* __restrict__ ew,
                       const int* __restrict__ off, int* __restrict__ cnt2,
                       int* __restrict__ ptok, int2* __restrict__ inv) {
    int t = blockIdx.x * blockDim.x + threadIdx.x;
    if (t >= T_TOK) return;
    int2 e = eidx[t];
    int p0 = off[e.x] + atomicAdd(&cnt2[e.x], 1);
    ptok[p0] = t;
    int p1 = off[e.y] + atomicAdd(&cnt2[e.y], 1);
    ptok[p1] = t;
    inv[t] = make_int2(p0, p1);
}

// ---- grouped GEMM1: h = silu(X Wg^T) * (X Wu^T) ------------------------
// BM=256 x BN=64 x BK=64, 512 thr = 8 waves (4m x 2n), wave tile 64x32.
// 1D grid, XCD-chunk swizzle; orig = ((e*64)+nb8)*8 + mt (mt innermost).
__global__ __launch_bounds__(512, 4) void k_gemm1(
        const ushort* __restrict__ xb, const float* __restrict__ wg,
        const float* __restrict__ wu, const int* __restrict__ ptok,
        const int* __restrict__ off, ushort* __restrict__ hbuf) {
    __shared__ __align__(16) ushort As[256 * 64];   // 32 KB
    __shared__ __align__(16) ushort Bg[64 * 64];    //  8 KB
    __shared__ __align__(16) ushort Bu[64 * 64];    //  8 KB

    // XCD swizzle: nwg = 4096 = 8e * 64nb * 8mt, cpx = 512
    int bid = blockIdx.x;
    int orig = (bid & 7) * 512 + (bid >> 3);
    int mt = orig & 7;
    int nbt = (orig >> 3) & 63;
    int e = orig >> 9;

    int base = off[e], ne = off[e + 1] - base;
    int row0 = mt * 256;
    if (row0 >= ne) return;
    int nb = nbt * 64;

    int tid = threadIdx.x;
    int wv = tid >> 6, l = tid & 63;
    int lr = l & 15, lk = l >> 4;
    int wm = wv >> 1, wn = wv & 1;

    int arow = tid >> 1, ah = (tid & 1) * 4;
    int p = base + min(row0 + arow, ne - 1);
    const ushort* xrow = xb + (size_t)ptok[p] * H_DIM;
    int asw = (arow & 7) << 4;
    int ao[4];
    #pragma unroll
    for (int j = 0; j < 4; j++)
        ao[j] = arow * 64 + ((((ah + j) * 16) ^ asw) >> 1);

    int brow = tid >> 3, bs = tid & 7;
    const float* wgrow = wg + ((size_t)e * F_DIM + nb + brow) * H_DIM + bs * 8;
    const float* wurow = wu + ((size_t)e * F_DIM + nb + brow) * H_DIM + bs * 8;
    int bo = brow * 64 + (((bs * 16) ^ ((brow & 7) << 4)) >> 1);

    int rsw = (lr & 7) << 4;

    f32x4 accg[4][2] = {}; f32x4 accu[4][2] = {};

    for (int kb = 0; kb < H_DIM; kb += 64) {
        __syncthreads();
        #pragma unroll
        for (int j = 0; j < 4; j++)
            *(uint4*)(&As[ao[j]]) = *(const uint4*)(xrow + kb + (ah + j) * 8);
        float4 g0 = *(const float4*)(wgrow + kb);
        float4 g1 = *(const float4*)(wgrow + kb + 4);
        *(uint4*)(&Bg[bo]) = pack8(g0, g1);
        float4 u0 = *(const float4*)(wurow + kb);
        float4 u1 = *(const float4*)(wurow + kb + 4);
        *(uint4*)(&Bu[bo]) = pack8(u0, u1);
        __syncthreads();

        #pragma unroll
        for (int kk = 0; kk < 2; kk++) {
            int kby = kk * 64 + lk * 16;
            short8 a[4];
            #pragma unroll
            for (int m = 0; m < 4; m++) {
                int row = wm * 64 + m * 16 + lr;
                a[m] = *(const short8*)(&As[(row * 128 + (kby ^ rsw)) >> 1]);
            }
            #pragma unroll
            for (int n = 0; n < 2; n++) {
                int rowb = wn * 32 + n * 16 + lr;
                int boff = (rowb * 128 + (kby ^ rsw)) >> 1;
                short8 bg8 = *(const short8*)(&Bg[boff]);
                short8 bu8 = *(const short8*)(&Bu[boff]);
                #pragma unroll
                for (int m = 0; m < 4; m++) {
                    accg[m][n] = __builtin_amdgcn_mfma_f32_16x16x32_bf16(a[m], bg8, accg[m][n], 0, 0, 0);
                    accu[m][n] = __builtin_amdgcn_mfma_f32_16x16x32_bf16(a[m], bu8, accu[m][n], 0, 0, 0);
                }
            }
        }
    }

    #pragma unroll
    for (int m = 0; m < 4; m++) {
        #pragma unroll
        for (int r = 0; r < 4; r++) {
            int lrow = wm * 64 + m * 16 + lk * 4 + r;
            if (row0 + lrow < ne) {
                size_t rb = (size_t)(base + row0 + lrow) * F_DIM + nb;
                #pragma unroll
                for (int n = 0; n < 2; n++) {
                    float g = accg[m][n][r], u = accu[m][n][r];
                    float hv = g / (1.f + __expf(-g)) * u;
                    hbuf[rb + wn * 32 + n * 16 + lr] = f2bf(hv);
                }
            }
        }
    }
}

// ---- grouped GEMM2: ybuf[p] = h[p] Wd^T --------------------------------
// BM=256 x BN=128 x BK=64, 512 thr = 8 waves (4m x 2n), wave tile 64x64.
// 1D grid, XCD-chunk swizzle; orig = ((e*16)+nb16)*8 + mt.
__global__ __launch_bounds__(512, 2) void k_gemm2(
        const ushort* __restrict__ hbuf, const float* __restrict__ wd,
        const int* __restrict__ off, float* __restrict__ ybuf) {
    __shared__ __align__(16) ushort As[256 * 64];   // 32 KB
    __shared__ __align__(16) ushort Bs[128 * 64];   // 16 KB

    // XCD swizzle: nwg = 1024 = 8e * 16nb * 8mt, cpx = 128
    int bid = blockIdx.x;
    int orig = (bid & 7) * 128 + (bid >> 3);
    int mt = orig & 7;
    int nbt = (orig >> 3) & 15;
    int e = orig >> 7;

    int base = off[e], ne = off[e + 1] - base;
    int row0 = mt * 256;
    if (row0 >= ne) return;
    int nb = nbt * 128;

    int tid = threadIdx.x;
    int wv = tid >> 6, l = tid & 63;
    int lr = l & 15, lk = l >> 4;
    int wm = wv >> 1, wn = wv & 1;

    int arow = tid >> 1, ah = (tid & 1) * 4;
    int p = base + min(row0 + arow, ne - 1);
    const ushort* hrow = hbuf + (size_t)p * F_DIM;
    int asw = (arow & 7) << 4;
    int ao[4];
    #pragma unroll
    for (int j = 0; j < 4; j++)
        ao[j] = arow * 64 + ((((ah + j) * 16) ^ asw) >> 1);

    int brow = tid >> 2, bs = tid & 3;
    const float* wdrow = wd + ((size_t)e * H_DIM + nb + brow) * F_DIM + bs * 16;
    int bsw = (brow & 7) << 4;
    int bo0 = brow * 64 + (((bs * 32) ^ bsw) >> 1);
    int bo1 = brow * 64 + (((bs * 32 + 16) ^ bsw) >> 1);

    int rsw = (lr & 7) << 4;

    f32x4 acc[4][4] = {};

    for (int kb = 0; kb < F_DIM; kb += 64) {
        __syncthreads();
        #pragma unroll
        for (int j = 0; j < 4; j++)
            *(uint4*)(&As[ao[j]]) = *(const uint4*)(hrow + kb + (ah + j) * 8);
        float4 b0 = *(const float4*)(wdrow + kb);
        float4 b1 = *(const float4*)(wdrow + kb + 4);
        float4 b2 = *(const float4*)(wdrow + kb + 8);
        float4 b3 = *(const float4*)(wdrow + kb + 12);
        *(uint4*)(&Bs[bo0]) = pack8(b0, b1);
        *(uint4*)(&Bs[bo1]) = pack8(b2, b3);
        __syncthreads();

        #pragma unroll
        for (int kk = 0; kk < 2; kk++) {
            int kby = kk * 64 + lk * 16;
            short8 a[4];
            #pragma unroll
            for (int m = 0; m < 4; m++) {
                int row = wm * 64 + m * 16 + lr;
                a[m] = *(const short8*)(&As[(row * 128 + (kby ^ rsw)) >> 1]);
            }
            #pragma unroll
            for (int n = 0; n < 4; n++) {
                int rowb = wn * 64 + n * 16 + lr;
                short8 b8 = *(const short8*)(&Bs[(rowb * 128 + (kby ^ rsw)) >> 1]);
                #pragma unroll
                for (int m = 0; m < 4; m++)
                    acc[m][n] = __builtin_amdgcn_mfma_f32_16x16x32_bf16(a[m], b8, acc[m][n], 0, 0, 0);
            }
        }
    }

    #pragma unroll
    for (int m = 0; m < 4; m++) {
        #pragma unroll
        for (int r = 0; r < 4; r++) {
            int lrow = wm * 64 + m * 16 + lk * 4 + r;
            if (row0 + lrow < ne) {
                float* yrow = ybuf + (size_t)(base + row0 + lrow) * H_DIM + nb;
                #pragma unroll
                for (int n = 0; n < 4; n++)
                    yrow[wn * 64 + n * 16 + lr] = acc[m][n][r];
            }
        }
    }
}

// ---- combine: out[t] = w0*y[p0] + w1*y[p1] -----------------------------
__global__ void k_combine(const float* __restrict__ ybuf,
                          const float2* __restrict__ ew,
                          const int2* __restrict__ inv,
                          float* __restrict__ out) {
    int t = blockIdx.x;
    float2 w = ew[t];
    int2 pp = inv[t];
    const float4* y0 = (const float4*)(ybuf + (size_t)pp.x * H_DIM);
    const float4* y1 = (const float4*)(ybuf + (size_t)pp.y * H_DIM);
    float4* o = (float4*)(out + (size_t)t * H_DIM);
    for (int j = threadIdx.x; j < H_DIM / 4; j += blockDim.x) {
        float4 a = y0[j], b = y1[j];
        float4 r;
        r.x = w.x * a.x + w.y * b.x;
        r.y = w.x * a.y + w.y * b.y;
        r.z = w.x * a.z + w.y * b.z;
        r.w = w.x * a.w + w.y * b.w;
        o[j] = r;
    }
}

extern "C" void kernel_launch(void* const* d_in, const int* in_sizes, int n_in,
                              void* d_out, int out_size, void* d_ws, size_t ws_size,
                              hipStream_t stream) {
    const float* x  = (const float*)d_in[0];
    const float* gw = (const float*)d_in[1];
    const float* wg = (const float*)d_in[2];
    const float* wu = (const float*)d_in[3];
    const float* wd = (const float*)d_in[4];
    float* out = (float*)d_out;

    char* ws = (char*)d_ws;
    size_t o = 0;
    ushort* xb   = (ushort*)(ws + o); o += (size_t)T_TOK * H_DIM * 2;   //  8 MB
    ushort* hbuf = (ushort*)(ws + o); o += (size_t)NPAIR * F_DIM * 2;   // 32 MB
    float*  ybuf = (float*) (ws + o); o += (size_t)NPAIR * H_DIM * 4;   // 32 MB
    int*    ptok = (int*)   (ws + o); o += NPAIR * 4;
    int2*   eidx = (int2*)  (ws + o); o += T_TOK * 8;
    float2* ew   = (float2*)(ws + o); o += T_TOK * 8;
    int2*   inv  = (int2*)  (ws + o); o += T_TOK * 8;
    int*    cnt  = (int*)   (ws + o); o += 256;
    int*    cnt2 = (int*)   (ws + o); o += 256;
    int*    off  = (int*)   (ws + o); o += 256;

    hipMemsetAsync(cnt, 0, 256, stream);

    k_cvt_x <<<T_TOK * H_DIM / 8 / 256, 256, 0, stream>>>(x, xb);
    k_router<<<T_TOK / 4, 256, 0, stream>>>(x, gw, eidx, ew, cnt);
    k_off   <<<1, 64, 0, stream>>>(cnt, off, cnt2);
    k_fill  <<<T_TOK / 256, 256, 0, stream>>>(eidx, ew, off, cnt2, ptok, inv);

    // 1D swizzled grids (mt innermost -> weight-panel siblings same XCD)
    k_gemm1<<<4096, 512, 0, stream>>>(xb, wg, wu, ptok, off, hbuf);
    k_gemm2<<<1024, 512, 0, stream>>>(hbuf, wd, off, ybuf);
    k_combine<<<T_TOK, 256, 0, stream>>>(ybuf, ew, inv, out);
}

// Round 11
// 669.424 us; speedup vs baseline: 1.4273x; 1.0608x over previous
//
#include <hip/hip_runtime.h>
#include <hip/hip_bf16.h>

// MiniMax MoE top-2, MI355X. T=2048, H=2048, F=4096, E=8.
// Round 11: gemm1 split into two single-output passes using the PROVEN
// gemm2 geometry (BM256 x BN128 x BK64, 8 waves, wave 64x64, acc 64 AGPR):
//   pass g: hbuf = X Wg^T (bf16)
//   pass u: u = X Wu^T; epilogue reads g from hbuf, writes silu(g)*u in place.
// gemm2 / router / combine / grids exactly as round 5 (best: 592us).

#define T_TOK 2048
#define H_DIM 2048
#define F_DIM 4096
#define E_NUM 8
#define NPAIR (T_TOK * 2)

typedef __attribute__((ext_vector_type(8))) short short8;
typedef __attribute__((ext_vector_type(4))) float f32x4;

__device__ __forceinline__ unsigned short f2bf(float f) {
    unsigned u = __builtin_bit_cast(unsigned, f);
    u = (u + 0x7FFFu + ((u >> 16) & 1u)) >> 16;   // RNE
    return (unsigned short)u;
}

__device__ __forceinline__ float bf2f(unsigned short us) {
    unsigned u = ((unsigned)us) << 16;
    return __builtin_bit_cast(float, u);
}

__device__ __forceinline__ uint4 pack8(float4 a, float4 b) {
    uint4 o;
    o.x = f2bf(a.x) | ((unsigned)f2bf(a.y) << 16);
    o.y = f2bf(a.z) | ((unsigned)f2bf(a.w) << 16);
    o.z = f2bf(b.x) | ((unsigned)f2bf(b.y) << 16);
    o.w = f2bf(b.z) | ((unsigned)f2bf(b.w) << 16);
    return o;
}

__device__ __forceinline__ uint2 pack4(float4 a) {
    uint2 o;
    o.x = f2bf(a.x) | ((unsigned)f2bf(a.y) << 16);
    o.y = f2bf(a.z) | ((unsigned)f2bf(a.w) << 16);
    return o;
}

// ---- x fp32 -> bf16 ----------------------------------------------------
__global__ void k_cvt_x(const float* __restrict__ x, ushort* __restrict__ xb) {
    int i = blockIdx.x * blockDim.x + threadIdx.x;
    const float4* p = (const float4*)x + (size_t)i * 2;
    uint2 lo = pack4(p[0]), hi = pack4(p[1]);
    ((uint4*)xb)[i] = make_uint4(lo.x, lo.y, hi.x, hi.y);
}

// ---- router ------------------------------------------------------------
__global__ void k_router(const float* __restrict__ x, const float* __restrict__ gw,
                         int2* __restrict__ eidx, float2* __restrict__ ew,
                         int* __restrict__ cnt) {
    int t = blockIdx.x * 4 + (threadIdx.x >> 6);
    int lane = threadIdx.x & 63;
    const float* xr = x + (size_t)t * H_DIM;
    float l[E_NUM];
    #pragma unroll
    for (int e = 0; e < E_NUM; e++) {
        const float* wr = gw + (size_t)e * H_DIM;
        float acc = 0.f;
        for (int i = lane; i < H_DIM; i += 64) acc += xr[i] * wr[i];
        #pragma unroll
        for (int o = 32; o; o >>= 1) acc += __shfl_xor(acc, o);
        l[e] = acc;
    }
    if (lane == 0) {
        int e0 = 0;
        #pragma unroll
        for (int e = 1; e < E_NUM; e++) if (l[e] > l[e0]) e0 = e;
        int e1 = -1;
        #pragma unroll
        for (int e = 0; e < E_NUM; e++) {
            if (e == e0) continue;
            if (e1 < 0 || l[e] > l[e1]) e1 = e;
        }
        float s1 = expf(l[e1] - l[e0]);
        float w0 = 1.f / (1.f + s1);
        float w1 = s1 * w0;
        eidx[t] = make_int2(e0, e1);
        ew[t]   = make_float2(w0, w1);
        atomicAdd(&cnt[e0], 1);
        atomicAdd(&cnt[e1], 1);
    }
}

__global__ void k_off(const int* __restrict__ cnt, int* __restrict__ off,
                      int* __restrict__ cnt2) {
    if (threadIdx.x == 0) {
        int s = 0;
        for (int e = 0; e < E_NUM; e++) { off[e] = s; s += cnt[e]; cnt2[e] = 0; }
        off[E_NUM] = s;
    }
}

__global__ void k_fill(const int2* __restrict__ eidx, const float2* __restrict__ ew,
                       const int* __restrict__ off, int* __restrict__ cnt2,
                       int* __restrict__ ptok, int2* __restrict__ inv) {
    int t = blockIdx.x * blockDim.x + threadIdx.x;
    if (t >= T_TOK) return;
    int2 e = eidx[t];
    int p0 = off[e.x] + atomicAdd(&cnt2[e.x], 1);
    ptok[p0] = t;
    int p1 = off[e.y] + atomicAdd(&cnt2[e.y], 1);
    ptok[p1] = t;
    inv[t] = make_int2(p0, p1);
}

// ---- gemm1 type pass: acc = X W^T (W = wg or wu), gemm2-geometry --------
// BM=256 x BN=128 x BK=64, 512 thr = 8 waves (4m x 2n), wave tile 64x64.
// FUSE=0: hbuf = bf16(acc)   (g pass)
// FUSE=1: hbuf = bf16(silu(g)*acc), g read from hbuf  (u pass, in place)
template <int FUSE>
__global__ __launch_bounds__(512, 2) void k_gemm1t(
        const ushort* __restrict__ xb, const float* __restrict__ w,
        const int* __restrict__ ptok, const int* __restrict__ off,
        ushort* __restrict__ hbuf) {
    __shared__ __align__(16) ushort As[256 * 64];   // 32 KB
    __shared__ __align__(16) ushort Bs[128 * 64];   // 16 KB

    int e = blockIdx.y >> 3, mt = blockIdx.y & 7;
    int base = off[e], ne = off[e + 1] - base;
    int row0 = mt * 256;
    if (row0 >= ne) return;
    int nb = blockIdx.x * 128;

    int tid = threadIdx.x;
    int wv = tid >> 6, l = tid & 63;
    int lr = l & 15, lk = l >> 4;
    int wm = wv >> 1, wn = wv & 1;

    // A staging: 2 thr/row (256 rows), 4x16B slots (proven map)
    int arow = tid >> 1, ah = (tid & 1) * 4;
    int p = base + min(row0 + arow, ne - 1);
    const ushort* xrow = xb + (size_t)ptok[p] * H_DIM;
    int asw = (arow & 7) << 4;
    int ao[4];
    #pragma unroll
    for (int j = 0; j < 4; j++)
        ao[j] = arow * 64 + ((((ah + j) * 16) ^ asw) >> 1);

    // B staging: 4 thr/row (128 rows), 16 floats -> two 16B slots (proven map)
    int brow = tid >> 2, bs = tid & 3;
    const float* wrow = w + ((size_t)e * F_DIM + nb + brow) * H_DIM + bs * 16;
    int bsw = (brow & 7) << 4;
    int bo0 = brow * 64 + (((bs * 32) ^ bsw) >> 1);
    int bo1 = brow * 64 + (((bs * 32 + 16) ^ bsw) >> 1);

    int rsw = (lr & 7) << 4;

    f32x4 acc[4][4] = {};

    for (int kb = 0; kb < H_DIM; kb += 64) {
        __syncthreads();
        #pragma unroll
        for (int j = 0; j < 4; j++)
            *(uint4*)(&As[ao[j]]) = *(const uint4*)(xrow + kb + (ah + j) * 8);
        float4 b0 = *(const float4*)(wrow + kb);
        float4 b1 = *(const float4*)(wrow + kb + 4);
        float4 b2 = *(const float4*)(wrow + kb + 8);
        float4 b3 = *(const float4*)(wrow + kb + 12);
        *(uint4*)(&Bs[bo0]) = pack8(b0, b1);
        *(uint4*)(&Bs[bo1]) = pack8(b2, b3);
        __syncthreads();

        #pragma unroll
        for (int kk = 0; kk < 2; kk++) {
            int kby = kk * 64 + lk * 16;
            short8 a[4];
            #pragma unroll
            for (int m = 0; m < 4; m++) {
                int row = wm * 64 + m * 16 + lr;
                a[m] = *(const short8*)(&As[(row * 128 + (kby ^ rsw)) >> 1]);
            }
            #pragma unroll
            for (int n = 0; n < 4; n++) {
                int rowb = wn * 64 + n * 16 + lr;
                short8 b8 = *(const short8*)(&Bs[(rowb * 128 + (kby ^ rsw)) >> 1]);
                #pragma unroll
                for (int m = 0; m < 4; m++)
                    acc[m][n] = __builtin_amdgcn_mfma_f32_16x16x32_bf16(a[m], b8, acc[m][n], 0, 0, 0);
            }
        }
    }

    // epilogue (C map: col=lane&15, row=(lane>>4)*4+r)
    #pragma unroll
    for (int m = 0; m < 4; m++) {
        #pragma unroll
        for (int r = 0; r < 4; r++) {
            int lrow = wm * 64 + m * 16 + lk * 4 + r;
            if (row0 + lrow < ne) {
                ushort* hb = hbuf + (size_t)(base + row0 + lrow) * F_DIM + nb;
                #pragma unroll
                for (int n = 0; n < 4; n++) {
                    int col = wn * 64 + n * 16 + lr;
                    if (FUSE) {
                        float g = bf2f(hb[col]);
                        float u = acc[m][n][r];
                        float hv = g / (1.f + __expf(-g)) * u;
                        hb[col] = f2bf(hv);
                    } else {
                        hb[col] = f2bf(acc[m][n][r]);
                    }
                }
            }
        }
    }
}

// ---- grouped GEMM2: ybuf[p] = h[p] Wd^T (exact round-5 body) -----------
__global__ __launch_bounds__(512, 2) void k_gemm2(
        const ushort* __restrict__ hbuf, const float* __restrict__ wd,
        const int* __restrict__ off, float* __restrict__ ybuf) {
    __shared__ __align__(16) ushort As[256 * 64];   // 32 KB
    __shared__ __align__(16) ushort Bs[128 * 64];   // 16 KB

    int e = blockIdx.y >> 3, mt = blockIdx.y & 7;
    int base = off[e], ne = off[e + 1] - base;
    int row0 = mt * 256;
    if (row0 >= ne) return;
    int nb = blockIdx.x * 128;

    int tid = threadIdx.x;
    int wv = tid >> 6, l = tid & 63;
    int lr = l & 15, lk = l >> 4;
    int wm = wv >> 1, wn = wv & 1;

    int arow = tid >> 1, ah = (tid & 1) * 4;
    int p = base + min(row0 + arow, ne - 1);
    const ushort* hrow = hbuf + (size_t)p * F_DIM;
    int asw = (arow & 7) << 4;
    int ao[4];
    #pragma unroll
    for (int j = 0; j < 4; j++)
        ao[j] = arow * 64 + ((((ah + j) * 16) ^ asw) >> 1);

    int brow = tid >> 2, bs = tid & 3;
    const float* wdrow = wd + ((size_t)e * H_DIM + nb + brow) * F_DIM + bs * 16;
    int bsw = (brow & 7) << 4;
    int bo0 = brow * 64 + (((bs * 32) ^ bsw) >> 1);
    int bo1 = brow * 64 + (((bs * 32 + 16) ^ bsw) >> 1);

    int rsw = (lr & 7) << 4;

    f32x4 acc[4][4] = {};

    for (int kb = 0; kb < F_DIM; kb += 64) {
        __syncthreads();
        #pragma unroll
        for (int j = 0; j < 4; j++)
            *(uint4*)(&As[ao[j]]) = *(const uint4*)(hrow + kb + (ah + j) * 8);
        float4 b0 = *(const float4*)(wdrow + kb);
        float4 b1 = *(const float4*)(wdrow + kb + 4);
        float4 b2 = *(const float4*)(wdrow + kb + 8);
        float4 b3 = *(const float4*)(wdrow + kb + 12);
        *(uint4*)(&Bs[bo0]) = pack8(b0, b1);
        *(uint4*)(&Bs[bo1]) = pack8(b2, b3);
        __syncthreads();

        #pragma unroll
        for (int kk = 0; kk < 2; kk++) {
            int kby = kk * 64 + lk * 16;
            short8 a[4];
            #pragma unroll
            for (int m = 0; m < 4; m++) {
                int row = wm * 64 + m * 16 + lr;
                a[m] = *(const short8*)(&As[(row * 128 + (kby ^ rsw)) >> 1]);
            }
            #pragma unroll
            for (int n = 0; n < 4; n++) {
                int rowb = wn * 64 + n * 16 + lr;
                short8 b8 = *(const short8*)(&Bs[(rowb * 128 + (kby ^ rsw)) >> 1]);
                #pragma unroll
                for (int m = 0; m < 4; m++)
                    acc[m][n] = __builtin_amdgcn_mfma_f32_16x16x32_bf16(a[m], b8, acc[m][n], 0, 0, 0);
            }
        }
    }

    #pragma unroll
    for (int m = 0; m < 4; m++) {
        #pragma unroll
        for (int r = 0; r < 4; r++) {
            int lrow = wm * 64 + m * 16 + lk * 4 + r;
            if (row0 + lrow < ne) {
                float* yrow = ybuf + (size_t)(base + row0 + lrow) * H_DIM + nb;
                #pragma unroll
                for (int n = 0; n < 4; n++)
                    yrow[wn * 64 + n * 16 + lr] = acc[m][n][r];
            }
        }
    }
}

// ---- combine: out[t] = w0*y[p0] + w1*y[p1] -----------------------------
__global__ void k_combine(const float* __restrict__ ybuf,
                          const float2* __restrict__ ew,
                          const int2* __restrict__ inv,
                          float* __restrict__ out) {
    int t = blockIdx.x;
    float2 w = ew[t];
    int2 pp = inv[t];
    const float4* y0 = (const float4*)(ybuf + (size_t)pp.x * H_DIM);
    const float4* y1 = (const float4*)(ybuf + (size_t)pp.y * H_DIM);
    float4* o = (float4*)(out + (size_t)t * H_DIM);
    for (int j = threadIdx.x; j < H_DIM / 4; j += blockDim.x) {
        float4 a = y0[j], b = y1[j];
        float4 r;
        r.x = w.x * a.x + w.y * b.x;
        r.y = w.x * a.y + w.y * b.y;
        r.z = w.x * a.z + w.y * b.z;
        r.w = w.x * a.w + w.y * b.w;
        o[j] = r;
    }
}

extern "C" void kernel_launch(void* const* d_in, const int* in_sizes, int n_in,
                              void* d_out, int out_size, void* d_ws, size_t ws_size,
                              hipStream_t stream) {
    const float* x  = (const float*)d_in[0];
    const float* gw = (const float*)d_in[1];
    const float* wg = (const float*)d_in[2];
    const float* wu = (const float*)d_in[3];
    const float* wd = (const float*)d_in[4];
    float* out = (float*)d_out;

    char* ws = (char*)d_ws;
    size_t o = 0;
    ushort* xb   = (ushort*)(ws + o); o += (size_t)T_TOK * H_DIM * 2;   //  8 MB
    ushort* hbuf = (ushort*)(ws + o); o += (size_t)NPAIR * F_DIM * 2;   // 32 MB
    float*  ybuf = (float*) (ws + o); o += (size_t)NPAIR * H_DIM * 4;   // 32 MB
    int*    ptok = (int*)   (ws + o); o += NPAIR * 4;
    int2*   eidx = (int2*)  (ws + o); o += T_TOK * 8;
    float2* ew   = (float2*)(ws + o); o += T_TOK * 8;
    int2*   inv  = (int2*)  (ws + o); o += T_TOK * 8;
    int*    cnt  = (int*)   (ws + o); o += 256;
    int*    cnt2 = (int*)   (ws + o); o += 256;
    int*    off  = (int*)   (ws + o); o += 256;

    hipMemsetAsync(cnt, 0, 256, stream);

    k_cvt_x <<<T_TOK * H_DIM / 8 / 256, 256, 0, stream>>>(x, xb);
    k_router<<<T_TOK / 4, 256, 0, stream>>>(x, gw, eidx, ew, cnt);
    k_off   <<<1, 64, 0, stream>>>(cnt, off, cnt2);
    k_fill  <<<T_TOK / 256, 256, 0, stream>>>(eidx, ew, off, cnt2, ptok, inv);

    dim3 g1(F_DIM / 128, E_NUM * 8);     // x: ntile(128) over F, y: e*8 + mtile(256)
    k_gemm1t<0><<<g1, 512, 0, stream>>>(xb, wg, ptok, off, hbuf);   // g pass
    k_gemm1t<1><<<g1, 512, 0, stream>>>(xb, wu, ptok, off, hbuf);   // u pass + silu*g in place
    dim3 g2(H_DIM / 128, E_NUM * 8);     // x: ntile(128) over H, y: e*8 + mtile(256)
    k_gemm2<<<g2, 512, 0, stream>>>(hbuf, wd, off, ybuf);
    k_combine<<<T_TOK, 256, 0, stream>>>(ybuf, ew, inv, out);
}

// Round 12
// 575.310 us; speedup vs baseline: 1.6607x; 1.1636x over previous
//
#include <hip/hip_runtime.h>
#include <hip/hip_bf16.h>

// MiniMax MoE top-2, MI355X. T=2048, H=2048, F=4096, E=8.
// Round 12: R5 bodies/grids (best proven 592us) + A-side global_load_lds:
//   - wave-uniform LDS chunk base via readfirstlane (R2 waterfall fix)
//   - linear LDS dest; XOR swizzle folded into per-lane GLOBAL source (m173)
//   - __syncthreads() drains vmcnt -> m97 structure. Weights stay reg-staged.

#define T_TOK 2048
#define H_DIM 2048
#define F_DIM 4096
#define E_NUM 8
#define NPAIR (T_TOK * 2)

typedef __attribute__((ext_vector_type(8))) short short8;
typedef __attribute__((ext_vector_type(4))) float f32x4;

__device__ __forceinline__ unsigned short f2bf(float f) {
    unsigned u = __builtin_bit_cast(unsigned, f);
    u = (u + 0x7FFFu + ((u >> 16) & 1u)) >> 16;   // RNE
    return (unsigned short)u;
}

__device__ __forceinline__ uint4 pack8(float4 a, float4 b) {
    uint4 o;
    o.x = f2bf(a.x) | ((unsigned)f2bf(a.y) << 16);
    o.y = f2bf(a.z) | ((unsigned)f2bf(a.w) << 16);
    o.z = f2bf(b.x) | ((unsigned)f2bf(b.y) << 16);
    o.w = f2bf(b.z) | ((unsigned)f2bf(b.w) << 16);
    return o;
}

__device__ __forceinline__ uint2 pack4(float4 a) {
    uint2 o;
    o.x = f2bf(a.x) | ((unsigned)f2bf(a.y) << 16);
    o.y = f2bf(a.z) | ((unsigned)f2bf(a.w) << 16);
    return o;
}

__device__ __forceinline__ void gload16(const void* g, void* s) {
    __builtin_amdgcn_global_load_lds(
        (const __attribute__((address_space(1))) unsigned int*)g,
        (__attribute__((address_space(3))) unsigned int*)s, 16, 0, 0);
}

// ---- x fp32 -> bf16 ----------------------------------------------------
__global__ void k_cvt_x(const float* __restrict__ x, ushort* __restrict__ xb) {
    int i = blockIdx.x * blockDim.x + threadIdx.x;
    const float4* p = (const float4*)x + (size_t)i * 2;
    uint2 lo = pack4(p[0]), hi = pack4(p[1]);
    ((uint4*)xb)[i] = make_uint4(lo.x, lo.y, hi.x, hi.y);
}

// ---- router ------------------------------------------------------------
__global__ void k_router(const float* __restrict__ x, const float* __restrict__ gw,
                         int2* __restrict__ eidx, float2* __restrict__ ew,
                         int* __restrict__ cnt) {
    int t = blockIdx.x * 4 + (threadIdx.x >> 6);
    int lane = threadIdx.x & 63;
    const float* xr = x + (size_t)t * H_DIM;
    float l[E_NUM];
    #pragma unroll
    for (int e = 0; e < E_NUM; e++) {
        const float* wr = gw + (size_t)e * H_DIM;
        float acc = 0.f;
        for (int i = lane; i < H_DIM; i += 64) acc += xr[i] * wr[i];
        #pragma unroll
        for (int o = 32; o; o >>= 1) acc += __shfl_xor(acc, o);
        l[e] = acc;
    }
    if (lane == 0) {
        int e0 = 0;
        #pragma unroll
        for (int e = 1; e < E_NUM; e++) if (l[e] > l[e0]) e0 = e;
        int e1 = -1;
        #pragma unroll
        for (int e = 0; e < E_NUM; e++) {
            if (e == e0) continue;
            if (e1 < 0 || l[e] > l[e1]) e1 = e;
        }
        float s1 = expf(l[e1] - l[e0]);
        float w0 = 1.f / (1.f + s1);
        float w1 = s1 * w0;
        eidx[t] = make_int2(e0, e1);
        ew[t]   = make_float2(w0, w1);
        atomicAdd(&cnt[e0], 1);
        atomicAdd(&cnt[e1], 1);
    }
}

__global__ void k_off(const int* __restrict__ cnt, int* __restrict__ off,
                      int* __restrict__ cnt2) {
    if (threadIdx.x == 0) {
        int s = 0;
        for (int e = 0; e < E_NUM; e++) { off[e] = s; s += cnt[e]; cnt2[e] = 0; }
        off[E_NUM] = s;
    }
}

__global__ void k_fill(const int2* __restrict__ eidx, const float2* __restrict__ ew,
                       const int* __restrict__ off, int* __restrict__ cnt2,
                       int* __restrict__ ptok, int2* __restrict__ inv) {
    int t = blockIdx.x * blockDim.x + threadIdx.x;
    if (t >= T_TOK) return;
    int2 e = eidx[t];
    int p0 = off[e.x] + atomicAdd(&cnt2[e.x], 1);
    ptok[p0] = t;
    int p1 = off[e.y] + atomicAdd(&cnt2[e.y], 1);
    ptok[p1] = t;
    inv[t] = make_int2(p0, p1);
}

// ---- grouped GEMM1: h = silu(X Wg^T) * (X Wu^T) ------------------------
// BM=256 x BN=64 x BK=64, 512 thr = 8 waves (4m x 2n), wave tile 64x32.
// A: global_load_lds, 4 x 1KB chunks/wave, pre-swizzled per-lane source.
__global__ __launch_bounds__(512, 4) void k_gemm1(
        const ushort* __restrict__ xb, const float* __restrict__ wg,
        const float* __restrict__ wu, const int* __restrict__ ptok,
        const int* __restrict__ off, ushort* __restrict__ hbuf) {
    __shared__ __align__(16) ushort As[256 * 64];   // 32 KB
    __shared__ __align__(16) ushort Bg[64 * 64];    //  8 KB
    __shared__ __align__(16) ushort Bu[64 * 64];    //  8 KB

    int e = blockIdx.y >> 4, mt = blockIdx.y & 15;
    int base = off[e], ne = off[e + 1] - base;
    int row0 = mt * 256;
    if (row0 >= ne) return;
    int nb = blockIdx.x * 64;

    int tid = threadIdx.x;
    int wv = tid >> 6, l = tid & 63;
    int lr = l & 15, lk = l >> 4;
    int wm = wv >> 1, wn = wv & 1;

    // A via gload_lds: chunk ch covers rows ch*8..ch*8+7 (1KB linear dest).
    // lane l -> row ch*8 + (l>>3); source slot = (l&7) ^ ((l>>3)&7) (inv swz).
    int wvu = __builtin_amdgcn_readfirstlane(wv);
    const ushort* srcA[4];
    int sslot = 8 * ((l & 7) ^ ((l >> 3) & 7));
    #pragma unroll
    for (int c = 0; c < 4; c++) {
        int r = (wvu * 4 + c) * 8 + (l >> 3);
        int pp = base + min(row0 + r, ne - 1);
        srcA[c] = xb + (size_t)ptok[pp] * H_DIM + sslot;
    }

    // B staging: 8 thr/row (64 rows), 8 floats -> one 16B slot each (R5 map)
    int brow = tid >> 3, bs = tid & 7;
    const float* wgrow = wg + ((size_t)e * F_DIM + nb + brow) * H_DIM + bs * 8;
    const float* wurow = wu + ((size_t)e * F_DIM + nb + brow) * H_DIM + bs * 8;
    int bo = brow * 64 + (((bs * 16) ^ ((brow & 7) << 4)) >> 1);

    int rsw = (lr & 7) << 4;

    f32x4 accg[4][2] = {}; f32x4 accu[4][2] = {};

    for (int kb = 0; kb < H_DIM; kb += 64) {
        __syncthreads();
        #pragma unroll
        for (int c = 0; c < 4; c++)
            gload16(srcA[c] + kb, (ushort*)As + (wvu * 4 + c) * 512);
        float4 g0 = *(const float4*)(wgrow + kb);
        float4 g1 = *(const float4*)(wgrow + kb + 4);
        *(uint4*)(&Bg[bo]) = pack8(g0, g1);
        float4 u0 = *(const float4*)(wurow + kb);
        float4 u1 = *(const float4*)(wurow + kb + 4);
        *(uint4*)(&Bu[bo]) = pack8(u0, u1);
        __syncthreads();   // drains vmcnt (gload_lds) + lgkm before MFMA

        #pragma unroll
        for (int kk = 0; kk < 2; kk++) {
            int kby = kk * 64 + lk * 16;
            short8 a[4];
            #pragma unroll
            for (int m = 0; m < 4; m++) {
                int row = wm * 64 + m * 16 + lr;
                a[m] = *(const short8*)(&As[(row * 128 + (kby ^ rsw)) >> 1]);
            }
            #pragma unroll
            for (int n = 0; n < 2; n++) {
                int rowb = wn * 32 + n * 16 + lr;
                int boff = (rowb * 128 + (kby ^ rsw)) >> 1;
                short8 bg8 = *(const short8*)(&Bg[boff]);
                short8 bu8 = *(const short8*)(&Bu[boff]);
                #pragma unroll
                for (int m = 0; m < 4; m++) {
                    accg[m][n] = __builtin_amdgcn_mfma_f32_16x16x32_bf16(a[m], bg8, accg[m][n], 0, 0, 0);
                    accu[m][n] = __builtin_amdgcn_mfma_f32_16x16x32_bf16(a[m], bu8, accu[m][n], 0, 0, 0);
                }
            }
        }
    }

    // epilogue: silu(g)*u (C map: col=lane&15, row=(lane>>4)*4+r)
    #pragma unroll
    for (int m = 0; m < 4; m++) {
        #pragma unroll
        for (int r = 0; r < 4; r++) {
            int lrow = wm * 64 + m * 16 + lk * 4 + r;
            if (row0 + lrow < ne) {
                size_t rb = (size_t)(base + row0 + lrow) * F_DIM + nb;
                #pragma unroll
                for (int n = 0; n < 2; n++) {
                    float g = accg[m][n][r], u = accu[m][n][r];
                    float hv = g / (1.f + __expf(-g)) * u;
                    hbuf[rb + wn * 32 + n * 16 + lr] = f2bf(hv);
                }
            }
        }
    }
}

// ---- grouped GEMM2: ybuf[p] = h[p] Wd^T --------------------------------
// BM=256 x BN=128 x BK=64, 512 thr = 8 waves (4m x 2n), wave tile 64x64.
// Same A-side gload_lds treatment.
__global__ __launch_bounds__(512, 2) void k_gemm2(
        const ushort* __restrict__ hbuf, const float* __restrict__ wd,
        const int* __restrict__ off, float* __restrict__ ybuf) {
    __shared__ __align__(16) ushort As[256 * 64];   // 32 KB
    __shared__ __align__(16) ushort Bs[128 * 64];   // 16 KB

    int e = blockIdx.y >> 3, mt = blockIdx.y & 7;
    int base = off[e], ne = off[e + 1] - base;
    int row0 = mt * 256;
    if (row0 >= ne) return;
    int nb = blockIdx.x * 128;

    int tid = threadIdx.x;
    int wv = tid >> 6, l = tid & 63;
    int lr = l & 15, lk = l >> 4;
    int wm = wv >> 1, wn = wv & 1;

    int wvu = __builtin_amdgcn_readfirstlane(wv);
    const ushort* srcA[4];
    int sslot = 8 * ((l & 7) ^ ((l >> 3) & 7));
    #pragma unroll
    for (int c = 0; c < 4; c++) {
        int r = (wvu * 4 + c) * 8 + (l >> 3);
        int pp = base + min(row0 + r, ne - 1);
        srcA[c] = hbuf + (size_t)pp * F_DIM + sslot;
    }

    // B staging: 4 thr/row (128 rows), 16 floats -> two 16B slots (R5 map)
    int brow = tid >> 2, bs = tid & 3;
    const float* wdrow = wd + ((size_t)e * H_DIM + nb + brow) * F_DIM + bs * 16;
    int bsw = (brow & 7) << 4;
    int bo0 = brow * 64 + (((bs * 32) ^ bsw) >> 1);
    int bo1 = brow * 64 + (((bs * 32 + 16) ^ bsw) >> 1);

    int rsw = (lr & 7) << 4;

    f32x4 acc[4][4] = {};

    for (int kb = 0; kb < F_DIM; kb += 64) {
        __syncthreads();
        #pragma unroll
        for (int c = 0; c < 4; c++)
            gload16(srcA[c] + kb, (ushort*)As + (wvu * 4 + c) * 512);
        float4 b0 = *(const float4*)(wdrow + kb);
        float4 b1 = *(const float4*)(wdrow + kb + 4);
        float4 b2 = *(const float4*)(wdrow + kb + 8);
        float4 b3 = *(const float4*)(wdrow + kb + 12);
        *(uint4*)(&Bs[bo0]) = pack8(b0, b1);
        *(uint4*)(&Bs[bo1]) = pack8(b2, b3);
        __syncthreads();

        #pragma unroll
        for (int kk = 0; kk < 2; kk++) {
            int kby = kk * 64 + lk * 16;
            short8 a[4];
            #pragma unroll
            for (int m = 0; m < 4; m++) {
                int row = wm * 64 + m * 16 + lr;
                a[m] = *(const short8*)(&As[(row * 128 + (kby ^ rsw)) >> 1]);
            }
            #pragma unroll
            for (int n = 0; n < 4; n++) {
                int rowb = wn * 64 + n * 16 + lr;
                short8 b8 = *(const short8*)(&Bs[(rowb * 128 + (kby ^ rsw)) >> 1]);
                #pragma unroll
                for (int m = 0; m < 4; m++)
                    acc[m][n] = __builtin_amdgcn_mfma_f32_16x16x32_bf16(a[m], b8, acc[m][n], 0, 0, 0);
            }
        }
    }

    #pragma unroll
    for (int m = 0; m < 4; m++) {
        #pragma unroll
        for (int r = 0; r < 4; r++) {
            int lrow = wm * 64 + m * 16 + lk * 4 + r;
            if (row0 + lrow < ne) {
                float* yrow = ybuf + (size_t)(base + row0 + lrow) * H_DIM + nb;
                #pragma unroll
                for (int n = 0; n < 4; n++)
                    yrow[wn * 64 + n * 16 + lr] = acc[m][n][r];
            }
        }
    }
}

// ---- combine: out[t] = w0*y[p0] + w1*y[p1] -----------------------------
__global__ void k_combine(const float* __restrict__ ybuf,
                          const float2* __restrict__ ew,
                          const int2* __restrict__ inv,
                          float* __restrict__ out) {
    int t = blockIdx.x;
    float2 w = ew[t];
    int2 pp = inv[t];
    const float4* y0 = (const float4*)(ybuf + (size_t)pp.x * H_DIM);
    const float4* y1 = (const float4*)(ybuf + (size_t)pp.y * H_DIM);
    float4* o = (float4*)(out + (size_t)t * H_DIM);
    for (int j = threadIdx.x; j < H_DIM / 4; j += blockDim.x) {
        float4 a = y0[j], b = y1[j];
        float4 r;
        r.x = w.x * a.x + w.y * b.x;
        r.y = w.x * a.y + w.y * b.y;
        r.z = w.x * a.z + w.y * b.z;
        r.w = w.x * a.w + w.y * b.w;
        o[j] = r;
    }
}

extern "C" void kernel_launch(void* const* d_in, const int* in_sizes, int n_in,
                              void* d_out, int out_size, void* d_ws, size_t ws_size,
                              hipStream_t stream) {
    const float* x  = (const float*)d_in[0];
    const float* gw = (const float*)d_in[1];
    const float* wg = (const float*)d_in[2];
    const float* wu = (const float*)d_in[3];
    const float* wd = (const float*)d_in[4];
    float* out = (float*)d_out;

    char* ws = (char*)d_ws;
    size_t o = 0;
    ushort* xb   = (ushort*)(ws + o); o += (size_t)T_TOK * H_DIM * 2;   //  8 MB
    ushort* hbuf = (ushort*)(ws + o); o += (size_t)NPAIR * F_DIM * 2;   // 32 MB
    float*  ybuf = (float*) (ws + o); o += (size_t)NPAIR * H_DIM * 4;   // 32 MB
    int*    ptok = (int*)   (ws + o); o += NPAIR * 4;
    int2*   eidx = (int2*)  (ws + o); o += T_TOK * 8;
    float2* ew   = (float2*)(ws + o); o += T_TOK * 8;
    int2*   inv  = (int2*)  (ws + o); o += T_TOK * 8;
    int*    cnt  = (int*)   (ws + o); o += 256;
    int*    cnt2 = (int*)   (ws + o); o += 256;
    int*    off  = (int*)   (ws + o); o += 256;

    hipMemsetAsync(cnt, 0, 256, stream);

    k_cvt_x <<<T_TOK * H_DIM / 8 / 256, 256, 0, stream>>>(x, xb);
    k_router<<<T_TOK / 4, 256, 0, stream>>>(x, gw, eidx, ew, cnt);
    k_off   <<<1, 64, 0, stream>>>(cnt, off, cnt2);
    k_fill  <<<T_TOK / 256, 256, 0, stream>>>(eidx, ew, off, cnt2, ptok, inv);

    dim3 g1(F_DIM / 64, E_NUM * 16);     // x: ntile(64), y: e*16 + mtile(256)
    k_gemm1<<<g1, 512, 0, stream>>>(xb, wg, wu, ptok, off, hbuf);
    dim3 g2(H_DIM / 128, E_NUM * 8);     // x: ntile(128), y: e*8 + mtile(256)
    k_gemm2<<<g2, 512, 0, stream>>>(hbuf, wd, off, ybuf);
    k_combine<<<T_TOK, 256, 0, stream>>>(ybuf, ew, inv, out);
}